// Round 1
// baseline (1838.949 us; speedup 1.0000x reference)
//
#include <hip/hip_runtime.h>
#include <math.h>

#define DM     2048
#define DMH    1024
#define DC     256
#define NSLOT  128
#define DSLOT  273
#define KPAD   288
#define MTOT   16384
#define CROWS  1536
#define SLOT0  384

// ---------------- LN row stats (mu, rsqrt(var+eps)), zero logits ----------------
__global__ __launch_bounds__(256) void k_ln_stats(const float* __restrict__ x,
    float* __restrict__ mu, float* __restrict__ rsig, float* __restrict__ logits)
{
    int row = blockIdx.x;
    const float* xr = x + (size_t)row * DM;
    int t = threadIdx.x;
    float4 v0 = *(const float4*)(xr + t * 4);
    float4 v1 = *(const float4*)(xr + 1024 + t * 4);
    float s = v0.x + v0.y + v0.z + v0.w + v1.x + v1.y + v1.z + v1.w;
#pragma unroll
    for (int m = 1; m < 64; m <<= 1) s += __shfl_xor(s, m);
    __shared__ float red[4];
    if ((t & 63) == 0) red[t >> 6] = s;
    __syncthreads();
    float mean = (red[0] + red[1] + red[2] + red[3]) * (1.0f / DM);
    float q = 0.f, d;
    d = v0.x - mean; q += d * d;  d = v0.y - mean; q += d * d;
    d = v0.z - mean; q += d * d;  d = v0.w - mean; q += d * d;
    d = v1.x - mean; q += d * d;  d = v1.y - mean; q += d * d;
    d = v1.z - mean; q += d * d;  d = v1.w - mean; q += d * d;
#pragma unroll
    for (int m = 1; m < 64; m <<= 1) q += __shfl_xor(q, m);
    __syncthreads();
    if ((t & 63) == 0) red[t >> 6] = q;
    __syncthreads();
    float var = (red[0] + red[1] + red[2] + red[3]) * (1.0f / DM);
    if (t == 0) { mu[row] = mean; rsig[row] = rsqrtf(var + 1e-5f); logits[row] = 0.f; }
}

// ---------------- zero-pad fc_w [273][2048] -> [288][2048] ----------------
__global__ __launch_bounds__(256) void k_pad_fcw(const float* __restrict__ fcw, float* __restrict__ dst)
{
    int idx = blockIdx.x * 256 + threadIdx.x;   // KPAD*DM total
    int row = idx >> 11;
    dst[idx] = (row < DSLOT) ? fcw[idx] : 0.f;  // same flat layout for row<273
}

// ---------------- fp32 tiled GEMM, 128x128 tile, 8x8 micro, BK=16 ----------------
// MODE 0: A = LN(x) on the fly; epilogue silu(acc+g1_b) . g2_w -> atomicAdd logits
// MODE 1: plain A; epilogue acc+bias -> outc
// MODE 2: plain A; epilogue acc+bias -> outc(context), x + gate*ctx -> outxe
#define BM 128
#define BN 128
#define BK 16
#define AP 132

template<int MODE>
__global__ __launch_bounds__(256) void k_gemm(
    const float* __restrict__ A, const float* __restrict__ Bw,
    int K, int lda, int ldb,
    const float* __restrict__ mu, const float* __restrict__ rsig,
    const float* __restrict__ lnw, const float* __restrict__ lnb,
    const float* __restrict__ bias,
    const float* __restrict__ g2w, const float* __restrict__ g2b,
    float* __restrict__ logits,
    float* __restrict__ outc, int ldc,
    const float* __restrict__ xin, float* __restrict__ outxe)
{
    __shared__ float As[BK][AP];
    __shared__ float Bs[BK][AP];
    __shared__ float mus[BM], rss[BM];
    int tid = threadIdx.x;
    int n0 = blockIdx.x * BN;
    int m0 = blockIdx.y * BM;
    int ty = tid >> 4, tx = tid & 15;
    int arow = tid >> 2;            // 0..63
    int akq  = (tid & 3) << 2;      // 0,4,8,12
    int brow = tid >> 4;            // 0..15
    int bnq  = (tid & 15) << 2;     // 0..60

    if (MODE == 0 && tid < BM) { mus[tid] = mu[m0 + tid]; rss[tid] = rsig[m0 + tid]; }

    float acc[8][8];
#pragma unroll
    for (int i = 0; i < 8; i++)
#pragma unroll
        for (int j = 0; j < 8; j++) acc[i][j] = 0.f;

    if (MODE == 0) __syncthreads();

    for (int k0 = 0; k0 < K; k0 += BK) {
        // A staging (transposed into As[k][m]); 2-way LDS write conflict = free
#pragma unroll
        for (int rr = 0; rr < 2; rr++) {
            int r = arow + rr * 64;
            float4 av = *(const float4*)(A + (size_t)(m0 + r) * lda + k0 + akq);
            if (MODE == 0) {
                float mm = mus[r], rs = rss[r];
                float4 w4 = *(const float4*)(lnw + k0 + akq);
                float4 b4 = *(const float4*)(lnb + k0 + akq);
                av.x = (av.x - mm) * rs * w4.x + b4.x;
                av.y = (av.y - mm) * rs * w4.y + b4.y;
                av.z = (av.z - mm) * rs * w4.z + b4.z;
                av.w = (av.w - mm) * rs * w4.w + b4.w;
            }
            As[akq + 0][r] = av.x;
            As[akq + 1][r] = av.y;
            As[akq + 2][r] = av.z;
            As[akq + 3][r] = av.w;
        }
        // B staging
#pragma unroll
        for (int cc = 0; cc < 2; cc++) {
            float4 bv = *(const float4*)(Bw + (size_t)(k0 + brow) * ldb + n0 + cc * 64 + bnq);
            *(float4*)&Bs[brow][cc * 64 + bnq] = bv;
        }
        __syncthreads();
#pragma unroll
        for (int k = 0; k < BK; k++) {
            float4 a0 = *(const float4*)&As[k][ty * 8];
            float4 a1 = *(const float4*)&As[k][ty * 8 + 4];
            float4 b0 = *(const float4*)&Bs[k][tx * 4];          // cols tx*4..+3
            float4 b1 = *(const float4*)&Bs[k][tx * 4 + 64];     // cols 64+tx*4..+3
            float a[8] = {a0.x,a0.y,a0.z,a0.w,a1.x,a1.y,a1.z,a1.w};
            float b[8] = {b0.x,b0.y,b0.z,b0.w,b1.x,b1.y,b1.z,b1.w};
#pragma unroll
            for (int i = 0; i < 8; i++)
#pragma unroll
                for (int j = 0; j < 8; j++) acc[i][j] += a[i] * b[j];
        }
        __syncthreads();
    }

    if (MODE == 0) {
        float4 bb0 = *(const float4*)(bias + n0 + tx * 4);
        float4 bb1 = *(const float4*)(bias + n0 + 64 + tx * 4);
        float4 gw0 = *(const float4*)(g2w + n0 + tx * 4);
        float4 gw1 = *(const float4*)(g2w + n0 + 64 + tx * 4);
        float bbv[8] = {bb0.x,bb0.y,bb0.z,bb0.w,bb1.x,bb1.y,bb1.z,bb1.w};
        float gwv[8] = {gw0.x,gw0.y,gw0.z,gw0.w,gw1.x,gw1.y,gw1.z,gw1.w};
#pragma unroll
        for (int i = 0; i < 8; i++) {
            float p = 0.f;
#pragma unroll
            for (int j = 0; j < 8; j++) {
                float v = acc[i][j] + bbv[j];
                float sg = v / (1.f + expf(-v));   // silu, accurate expf (gate precision)
                p += sg * gwv[j];
            }
#pragma unroll
            for (int m = 1; m < 16; m <<= 1) p += __shfl_xor(p, m);
            if (tx == 0) atomicAdd(&logits[m0 + ty * 8 + i], p);
        }
    } else if (MODE == 1) {
        float4 bb0 = *(const float4*)(bias + n0 + tx * 4);
        float4 bb1 = *(const float4*)(bias + n0 + 64 + tx * 4);
#pragma unroll
        for (int i = 0; i < 8; i++) {
            int m = m0 + ty * 8 + i;
            float4 c0 = {acc[i][0]+bb0.x, acc[i][1]+bb0.y, acc[i][2]+bb0.z, acc[i][3]+bb0.w};
            float4 c1 = {acc[i][4]+bb1.x, acc[i][5]+bb1.y, acc[i][6]+bb1.z, acc[i][7]+bb1.w};
            *(float4*)(outc + (size_t)m * ldc + n0 + tx * 4) = c0;
            *(float4*)(outc + (size_t)m * ldc + n0 + 64 + tx * 4) = c1;
        }
    } else {
        float g2bv = g2b[0];
        float4 bb0 = *(const float4*)(bias + n0 + tx * 4);
        float4 bb1 = *(const float4*)(bias + n0 + 64 + tx * 4);
#pragma unroll
        for (int i = 0; i < 8; i++) {
            int m = m0 + ty * 8 + i;
            float gt = (logits[m] + g2bv) > 0.f ? 1.f : 0.f;
            float4 c0 = {acc[i][0]+bb0.x, acc[i][1]+bb0.y, acc[i][2]+bb0.z, acc[i][3]+bb0.w};
            float4 c1 = {acc[i][4]+bb1.x, acc[i][5]+bb1.y, acc[i][6]+bb1.z, acc[i][7]+bb1.w};
            *(float4*)(outc + (size_t)m * ldc + n0 + tx * 4) = c0;
            *(float4*)(outc + (size_t)m * ldc + n0 + 64 + tx * 4) = c1;
            float4 x0 = *(const float4*)(xin + (size_t)m * DM + n0 + tx * 4);
            float4 x1 = *(const float4*)(xin + (size_t)m * DM + n0 + 64 + tx * 4);
            float4 e0 = {x0.x + gt*c0.x, x0.y + gt*c0.y, x0.z + gt*c0.z, x0.w + gt*c0.w};
            float4 e1 = {x1.x + gt*c1.x, x1.y + gt*c1.y, x1.z + gt*c1.z, x1.w + gt*c1.w};
            *(float4*)(outxe + (size_t)m * DM + n0 + tx * 4) = e0;
            *(float4*)(outxe + (size_t)m * DM + n0 + 64 + tx * 4) = e1;
        }
    }
}

// ---------------- attention: 16 q-rows per block, 128 slots ----------------
__global__ __launch_bounds__(256) void k_attn(const float* __restrict__ query,
    const float* __restrict__ cache, float* __restrict__ attn_out, float* __restrict__ ctxf)
{
    __shared__ float qs[16][260];      // query rows
    __shared__ float cs[128][68];      // content chunk [slot][64 d] (reused as local tile)
    __shared__ float as_[16][132];     // attn
    int tid = threadIdx.x;
    int m0 = blockIdx.x * 16;
    int b = m0 >> 12;
    const size_t cbase = ((size_t)b * CROWS + SLOT0) * DSLOT;

    // stage 16x256 query rows
#pragma unroll
    for (int i = 0; i < 4; i++) {
        int f = tid + i * 256;                 // float4 index over 16*64
        int row = f >> 6, c4 = f & 63;
        float4 v = *(const float4*)(query + (size_t)(m0 + row) * DC + c4 * 4);
        *(float4*)&qs[row][c4 * 4] = v;
    }
    int r = tid >> 4, tx = tid & 15;
    float sc[8];
#pragma unroll
    for (int j = 0; j < 8; j++) sc[j] = 0.f;

    for (int d0 = 0; d0 < DC; d0 += 64) {
        __syncthreads();
        for (int idx = tid; idx < 128 * 64; idx += 256) {
            int slot = idx >> 6, dd = idx & 63;
            cs[slot][dd] = cache[cbase + (size_t)slot * DSLOT + d0 + dd];
        }
        __syncthreads();
        for (int dd = 0; dd < 64; dd++) {
            float qv = qs[r][d0 + dd];
#pragma unroll
            for (int j = 0; j < 8; j++) sc[j] += qv * cs[tx + 16 * j][dd];
        }
    }
    // scale, clip, softmax over 128 (16 lanes x 8 each)
    float mx = -1e30f;
#pragma unroll
    for (int j = 0; j < 8; j++) {
        sc[j] *= 0.0625f;
        sc[j] = fminf(fmaxf(sc[j], -20.f), 20.f);
        mx = fmaxf(mx, sc[j]);
    }
#pragma unroll
    for (int m = 1; m < 16; m <<= 1) mx = fmaxf(mx, __shfl_xor(mx, m));
    float sum = 0.f;
#pragma unroll
    for (int j = 0; j < 8; j++) { float e = expf(sc[j] - mx); sc[j] = e; sum += e; }
#pragma unroll
    for (int m = 1; m < 16; m <<= 1) sum += __shfl_xor(sum, m);
    float inv = 1.f / sum;
#pragma unroll
    for (int j = 0; j < 8; j++) as_[r][tx + 16 * j] = sc[j] * inv;
    __syncthreads();

    // write attn output
#pragma unroll
    for (int i = 0; i < 2; i++) {
        int f = tid + i * 256;                 // float4 over 16*32
        int row = f >> 5, c4 = f & 31;
        float4 v = *(const float4*)&as_[row][c4 * 4];
        *(float4*)(attn_out + (size_t)(m0 + row) * NSLOT + c4 * 4) = v;
    }

    // PV: context_full[16][273] = attn @ local
    float* ls = &cs[0][0];
    float ctx[18];
#pragma unroll
    for (int i = 0; i < 18; i++) ctx[i] = 0.f;
    for (int k0 = 0; k0 < NSLOT; k0 += 16) {
        __syncthreads();
        for (int idx = tid; idx < 16 * DSLOT; idx += 256) {
            int kk = idx / DSLOT, c = idx % DSLOT;
            ls[kk * DSLOT + c] = cache[cbase + (size_t)(k0 + kk) * DSLOT + c];
        }
        __syncthreads();
#pragma unroll
        for (int kk = 0; kk < 16; kk++) {
            float a = as_[r][k0 + kk];
#pragma unroll
            for (int i = 0; i < 18; i++) {
                int c = tx + 16 * i;
                if (c < DSLOT) ctx[i] += a * ls[kk * DSLOT + c];
            }
        }
    }
    float* crow = ctxf + (size_t)(m0 + r) * KPAD;
#pragma unroll
    for (int i = 0; i < 18; i++) { int c = tx + 16 * i; if (c < DSLOT) crow[c] = ctx[i]; }
    if (tx < KPAD - DSLOT) crow[DSLOT + tx] = 0.f;
}

extern "C" void kernel_launch(void* const* d_in, const int* in_sizes, int n_in,
                              void* d_out, int out_size, void* d_ws, size_t ws_size,
                              hipStream_t stream)
{
    (void)in_sizes; (void)n_in; (void)out_size; (void)ws_size;
    const float* x    = (const float*)d_in[0];
    const float* cache= (const float*)d_in[1];
    const float* lnw  = (const float*)d_in[2];
    const float* lnb  = (const float*)d_in[3];
    const float* g1w  = (const float*)d_in[4];
    const float* g1b  = (const float*)d_in[5];
    const float* g2w  = (const float*)d_in[6];
    const float* g2b  = (const float*)d_in[7];
    const float* rqw  = (const float*)d_in[8];
    const float* rqb  = (const float*)d_in[9];
    const float* fcw  = (const float*)d_in[10];
    const float* fcb  = (const float*)d_in[11];

    float* out   = (float*)d_out;
    float* oxe   = out;
    float* octx  = out + (size_t)MTOT * DM;
    float* oattn = out + (size_t)2 * MTOT * DM;

    float* ws     = (float*)d_ws;
    float* mu     = ws;
    float* rsig   = ws + MTOT;
    float* logits = ws + 2 * MTOT;
    float* query  = ws + 3 * MTOT;
    float* ctxf   = query + (size_t)MTOT * DC;
    float* fcwp   = ctxf + (size_t)MTOT * KPAD;

    k_pad_fcw<<<(KPAD * DM) / 256, 256, 0, stream>>>(fcw, fcwp);
    k_ln_stats<<<MTOT, 256, 0, stream>>>(x, mu, rsig, logits);
    // gate chain: LN -> GEMM1 (+silu, g2 dot) -> logits
    k_gemm<0><<<dim3(DMH / BN, MTOT / BM), 256, 0, stream>>>(x, g1w, DM, DM, DMH,
        mu, rsig, lnw, lnb, g1b, g2w, g2b, logits, nullptr, 0, nullptr, nullptr);
    // query = x @ rq_w + rq_b
    k_gemm<1><<<dim3(DC / BN, MTOT / BM), 256, 0, stream>>>(x, rqw, DM, DM, DC,
        nullptr, nullptr, nullptr, nullptr, rqb, nullptr, nullptr, nullptr, query, DC, nullptr, nullptr);
    // attention
    k_attn<<<MTOT / 16, 256, 0, stream>>>(query, cache, oattn, ctxf);
    // context = ctxf @ fc_w + fc_b ; x_enhanced = x + gate*context
    k_gemm<2><<<dim3(DM / BN, MTOT / BM), 256, 0, stream>>>(ctxf, fcwp, KPAD, KPAD, DM,
        nullptr, nullptr, nullptr, nullptr, fcb, nullptr, g2b, logits, octx, DM, x, oxe);
}

// Round 2
// 1204.762 us; speedup vs baseline: 1.5264x; 1.5264x over previous
//
#include <hip/hip_runtime.h>
#include <math.h>

#define DM     2048
#define DMH    1024
#define DC     256
#define NSLOT  128
#define DSLOT  273
#define KPAD   288
#define MTOT   16384
#define CROWS  1536
#define SLOT0  384
#define MAXR   4096
#define TAU    2e-3f

typedef __attribute__((ext_vector_type(8))) short  short8;
typedef __attribute__((ext_vector_type(8))) __bf16 bf16x8;
typedef __attribute__((ext_vector_type(4))) float  f32x4;

__device__ inline ushort f2bf(float f) {
    unsigned u = __builtin_bit_cast(unsigned, f);
    unsigned r = (u + 0x7FFFu + ((u >> 16) & 1u)) >> 16;   // RNE
    return (ushort)r;
}
__device__ inline float bf2f(ushort h) {
    unsigned u = ((unsigned)h) << 16;
    return __builtin_bit_cast(float, u);
}

// ---------------- LN row stats; zero logits; zero count ----------------
__global__ __launch_bounds__(256) void k_ln_stats(const float* __restrict__ x,
    float* __restrict__ mu, float* __restrict__ rsig, float* __restrict__ logits,
    int* __restrict__ cnt)
{
    int row = blockIdx.x;
    const float* xr = x + (size_t)row * DM;
    int t = threadIdx.x;
    float4 v0 = *(const float4*)(xr + t * 4);
    float4 v1 = *(const float4*)(xr + 1024 + t * 4);
    float s = v0.x + v0.y + v0.z + v0.w + v1.x + v1.y + v1.z + v1.w;
#pragma unroll
    for (int m = 1; m < 64; m <<= 1) s += __shfl_xor(s, m);
    __shared__ float red[4];
    if ((t & 63) == 0) red[t >> 6] = s;
    __syncthreads();
    float mean = (red[0] + red[1] + red[2] + red[3]) * (1.0f / DM);
    float q = 0.f, d;
    d = v0.x - mean; q += d * d;  d = v0.y - mean; q += d * d;
    d = v0.z - mean; q += d * d;  d = v0.w - mean; q += d * d;
    d = v1.x - mean; q += d * d;  d = v1.y - mean; q += d * d;
    d = v1.z - mean; q += d * d;  d = v1.w - mean; q += d * d;
#pragma unroll
    for (int m = 1; m < 64; m <<= 1) q += __shfl_xor(q, m);
    __syncthreads();
    if ((t & 63) == 0) red[t >> 6] = q;
    __syncthreads();
    float var = (red[0] + red[1] + red[2] + red[3]) * (1.0f / DM);
    if (t == 0) { mu[row] = mean; rsig[row] = rsqrtf(var + 1e-5f); logits[row] = 0.f; }
    if (row == 0 && t == 0) *cnt = 0;
}

// ---------------- weights: convert + transpose to B^T [N][K] bf16 ----------------
__global__ __launch_bounds__(256) void k_prep_w(const float* __restrict__ g1w,
    const float* __restrict__ rqw, const float* __restrict__ fcw,
    ushort* __restrict__ Bh, ushort* __restrict__ Bl,
    ushort* __restrict__ rqwt, ushort* __restrict__ fcwt)
{
    int idx = blockIdx.x * 256 + threadIdx.x;     // 2,097,152 total
    {   // g1w [2048][1024] -> hi/lo [1024][2048]
        int nn = idx >> 11, k = idx & 2047;
        float v = g1w[(size_t)k * DMH + nn];
        ushort h = f2bf(v);
        Bh[idx] = h;
        Bl[idx] = f2bf(v - bf2f(h));
    }
    if (idx < DC * DM) {        // rqw [2048][256] -> [256][2048]
        int nn = idx >> 11, k = idx & 2047;
        rqwt[idx] = f2bf(rqw[(size_t)k * DC + nn]);
    }
    if (idx < DM * KPAD) {      // fcw [273][2048] -> [2048][288] zero-padded
        int nn = idx / KPAD, kk = idx - nn * KPAD;
        fcwt[idx] = (kk < DSLOT) ? f2bf(fcw[(size_t)kk * DM + nn]) : (ushort)0;
    }
}

// ---------------- A = LN(x): hi/lo bf16 split ----------------
__global__ __launch_bounds__(256) void k_prep_a(const float* __restrict__ x,
    const float* __restrict__ mu, const float* __restrict__ rsig,
    const float* __restrict__ lnw, const float* __restrict__ lnb,
    ushort* __restrict__ Ah, ushort* __restrict__ Al)
{
    int e8 = blockIdx.x * 256 + threadIdx.x;      // 4.19M chunks of 8
    int row = e8 >> 8, c = (e8 & 255) * 8;
    float mm = mu[row], rs = rsig[row];
    const float* xp = x + (size_t)row * DM + c;
    float4 a = *(const float4*)xp, b = *(const float4*)(xp + 4);
    float4 w0 = *(const float4*)(lnw + c), w1 = *(const float4*)(lnw + c + 4);
    float4 b0 = *(const float4*)(lnb + c), b1 = *(const float4*)(lnb + c + 4);
    float v[8] = {(a.x-mm)*rs*w0.x+b0.x, (a.y-mm)*rs*w0.y+b0.y,
                  (a.z-mm)*rs*w0.z+b0.z, (a.w-mm)*rs*w0.w+b0.w,
                  (b.x-mm)*rs*w1.x+b1.x, (b.y-mm)*rs*w1.y+b1.y,
                  (b.z-mm)*rs*w1.z+b1.z, (b.w-mm)*rs*w1.w+b1.w};
    ushort h[8]; uint4 oh, ol;
#pragma unroll
    for (int e = 0; e < 8; e++) h[e] = f2bf(v[e]);
    oh.x = h[0] | ((unsigned)h[1] << 16); oh.y = h[2] | ((unsigned)h[3] << 16);
    oh.z = h[4] | ((unsigned)h[5] << 16); oh.w = h[6] | ((unsigned)h[7] << 16);
#pragma unroll
    for (int e = 0; e < 8; e++) h[e] = f2bf(v[e] - bf2f(h[e]));
    ol.x = h[0] | ((unsigned)h[1] << 16); ol.y = h[2] | ((unsigned)h[3] << 16);
    ol.z = h[4] | ((unsigned)h[5] << 16); ol.w = h[6] | ((unsigned)h[7] << 16);
    *(uint4*)(Ah + (size_t)e8 * 8) = oh;
    *(uint4*)(Al + (size_t)e8 * 8) = ol;
}

// ---------------- xh = bf16(x) (into Al buffer, after gate GEMM) ----------------
__global__ __launch_bounds__(256) void k_prep_xh(const float* __restrict__ x, ushort* __restrict__ xh)
{
    int e8 = blockIdx.x * 256 + threadIdx.x;
    const float* xp = x + (size_t)e8 * 8;
    float4 a = *(const float4*)xp, b = *(const float4*)(xp + 4);
    float v[8] = {a.x,a.y,a.z,a.w,b.x,b.y,b.z,b.w};
    ushort h[8]; uint4 o;
#pragma unroll
    for (int e = 0; e < 8; e++) h[e] = f2bf(v[e]);
    o.x = h[0] | ((unsigned)h[1] << 16); o.y = h[2] | ((unsigned)h[3] << 16);
    o.z = h[4] | ((unsigned)h[5] << 16); o.w = h[6] | ((unsigned)h[7] << 16);
    *(uint4*)(xh + (size_t)e8 * 8) = o;
}

// ---------------- bf16 MFMA GEMM, 128x128 tile, BK=32, gemm_bt layout ----------------
// MODE 0: gate (3-seg split: AhBh + AhBl + AlBh), epilogue silu(.+g1b).g2w -> atomicAdd logits
// MODE 1: query: acc + bias -> outc fp32
// MODE 2: fc: acc + bias -> outc; outxe = xin + gate*val
template<int MODE>
__global__ __launch_bounds__(256) void k_mfma(
    const ushort* __restrict__ A0, const ushort* __restrict__ A1,
    const ushort* __restrict__ B0, const ushort* __restrict__ B1,
    int K, int N,
    const float* __restrict__ g1b, const float* __restrict__ g2w,
    float* __restrict__ logits,
    const float* __restrict__ bias, float* __restrict__ outc,
    const float* __restrict__ xin, float* __restrict__ outxe,
    const float* __restrict__ g2b)
{
    __shared__ __align__(16) ushort Asl[128 * 32];
    __shared__ __align__(16) ushort Bsl[128 * 32];
    int tid = threadIdx.x;
    int wid = tid >> 6, l = tid & 63;
    int m0 = blockIdx.y * 128, n0 = blockIdx.x * 128;
    int m_off = (wid >> 1) * 64, n_off = (wid & 1) * 64;
    int lr = l & 15, lk = l >> 4;
    int arow = l >> 2, ak8 = (l & 3) * 8;

    f32x4 acc[4][4];
#pragma unroll
    for (int i = 0; i < 4; i++)
#pragma unroll
        for (int j = 0; j < 4; j++) acc[i][j] = (f32x4){0.f, 0.f, 0.f, 0.f};

    const int NSEG = (MODE == 0) ? 3 : 1;
    for (int s = 0; s < NSEG; s++) {
        const ushort* As = (s == 2) ? A1 : A0;
        const ushort* Bs = (s == 1) ? B1 : B0;
        for (int k0 = 0; k0 < K; k0 += 32) {
#pragma unroll
            for (int q = 0; q < 2; q++) {
                int chunk = q * 4 + wid;
                int row = chunk * 16 + arow;
                const ushort* ga = As + (size_t)(m0 + row) * K + k0 + ak8;
                const ushort* gb = Bs + (size_t)(n0 + row) * K + k0 + ak8;
                __builtin_amdgcn_global_load_lds(
                    (const __attribute__((address_space(1))) void*)ga,
                    (__attribute__((address_space(3))) void*)(Asl + chunk * 512), 16, 0, 0);
                __builtin_amdgcn_global_load_lds(
                    (const __attribute__((address_space(1))) void*)gb,
                    (__attribute__((address_space(3))) void*)(Bsl + chunk * 512), 16, 0, 0);
            }
            __syncthreads();
            bf16x8 af[4], bfr[4];
#pragma unroll
            for (int i = 0; i < 4; i++)
                af[i] = __builtin_bit_cast(bf16x8, *(const short8*)&Asl[(m_off + i * 16 + lr) * 32 + lk * 8]);
#pragma unroll
            for (int j = 0; j < 4; j++)
                bfr[j] = __builtin_bit_cast(bf16x8, *(const short8*)&Bsl[(n_off + j * 16 + lr) * 32 + lk * 8]);
#pragma unroll
            for (int i = 0; i < 4; i++)
#pragma unroll
                for (int j = 0; j < 4; j++)
                    acc[i][j] = __builtin_amdgcn_mfma_f32_16x16x32_bf16(af[i], bfr[j], acc[i][j], 0, 0, 0);
            __syncthreads();
        }
    }

    if (MODE == 0) {
        float gb_[4], gw_[4];
#pragma unroll
        for (int j = 0; j < 4; j++) {
            int c = n0 + n_off + j * 16 + lr;
            gb_[j] = g1b[c]; gw_[j] = g2w[c];
        }
#pragma unroll
        for (int i = 0; i < 4; i++)
#pragma unroll
            for (int v = 0; v < 4; v++) {
                float p = 0.f;
#pragma unroll
                for (int j = 0; j < 4; j++) {
                    float h = acc[i][j][v] + gb_[j];
                    p += (h / (1.f + expf(-h))) * gw_[j];
                }
#pragma unroll
                for (int m = 1; m < 16; m <<= 1) p += __shfl_xor(p, m);
                if (lr == 0) atomicAdd(&logits[m0 + m_off + i * 16 + lk * 4 + v], p);
            }
    } else {
        float bias4[4];
#pragma unroll
        for (int j = 0; j < 4; j++) bias4[j] = bias[n0 + n_off + j * 16 + lr];
        float g2b0 = (MODE == 2) ? g2b[0] : 0.f;
#pragma unroll
        for (int i = 0; i < 4; i++)
#pragma unroll
            for (int v = 0; v < 4; v++) {
                int m = m0 + m_off + i * 16 + lk * 4 + v;
                float gt = 0.f;
                if (MODE == 2) gt = (logits[m] + g2b0) > 0.f ? 1.f : 0.f;
#pragma unroll
                for (int j = 0; j < 4; j++) {
                    int c = n0 + n_off + j * 16 + lr;
                    float val = acc[i][j][v] + bias4[j];
                    outc[(size_t)m * N + c] = val;
                    if (MODE == 2) outxe[(size_t)m * DM + c] = xin[(size_t)m * DM + c] + gt * val;
                }
            }
    }
}

// ---------------- flag rows with |logit+g2b| < TAU ----------------
__global__ __launch_bounds__(256) void k_compact(float* __restrict__ logits,
    const float* __restrict__ g2b, int* __restrict__ cnt, int* __restrict__ list)
{
    int i = blockIdx.x * 256 + threadIdx.x;
    float a = logits[i] + g2b[0];
    if (fabsf(a) < TAU) {
        int p = atomicAdd(cnt, 1);
        if (p < MAXR) { list[p] = i; logits[i] = 0.f; }
    }
}

// ---------------- exact fp32 logit recompute for flagged rows ----------------
__global__ __launch_bounds__(256) void k_refine(const float* __restrict__ x,
    const float* __restrict__ mu, const float* __restrict__ rsig,
    const float* __restrict__ lnw, const float* __restrict__ lnb,
    const float* __restrict__ g1w, const float* __restrict__ g1b,
    const float* __restrict__ g2w,
    const int* __restrict__ list, const int* __restrict__ cnt,
    float* __restrict__ logits)
{
    __shared__ float lnx[DM];
    __shared__ float red[256];
    int tid = threadIdx.x;
    int n = *cnt; if (n > MAXR) n = MAXR;
    int ntask = n * 8;
    for (int t = blockIdx.x; t < ntask; t += gridDim.x) {
        int row = list[t >> 3], sl = t & 7;
        float mm = mu[row], rs = rsig[row];
        {
            int c = tid * 8;
            const float* xp = x + (size_t)row * DM + c;
            float4 a = *(const float4*)xp, b = *(const float4*)(xp + 4);
            float4 w0 = *(const float4*)(lnw + c), w1 = *(const float4*)(lnw + c + 4);
            float4 b0 = *(const float4*)(lnb + c), b1 = *(const float4*)(lnb + c + 4);
            lnx[c+0] = (a.x-mm)*rs*w0.x+b0.x; lnx[c+1] = (a.y-mm)*rs*w0.y+b0.y;
            lnx[c+2] = (a.z-mm)*rs*w0.z+b0.z; lnx[c+3] = (a.w-mm)*rs*w0.w+b0.w;
            lnx[c+4] = (b.x-mm)*rs*w1.x+b1.x; lnx[c+5] = (b.y-mm)*rs*w1.y+b1.y;
            lnx[c+6] = (b.z-mm)*rs*w1.z+b1.z; lnx[c+7] = (b.w-mm)*rs*w1.w+b1.w;
        }
        __syncthreads();
        int j0 = tid & 127, half = tid >> 7;
        int col = sl * 128 + j0;
        const float* gp = g1w + (size_t)(half * 1024) * DMH + col;
        const float* lp = lnx + half * 1024;
        float s = 0.f;
#pragma unroll 4
        for (int k = 0; k < 1024; k++) s += lp[k] * gp[(size_t)k * DMH];
        red[tid] = s;
        __syncthreads();
        if (tid < 128) {
            float h = red[tid] + red[tid + 128] + g1b[col];
            float p = (h / (1.f + expf(-h))) * g2w[col];
#pragma unroll
            for (int m = 1; m < 64; m <<= 1) p += __shfl_xor(p, m);
            red[tid] = p;
        }
        __syncthreads();
        if (tid == 0) atomicAdd(&logits[row], red[0] + red[64]);
        __syncthreads();
    }
}

// ---------------- attention: 16 q-rows per block, 128 slots ----------------
__global__ __launch_bounds__(256) void k_attn(const float* __restrict__ query,
    const float* __restrict__ cache, float* __restrict__ attn_out, ushort* __restrict__ ctxb)
{
    __shared__ float qs[16][260];
    __shared__ float cs[128][68];
    __shared__ float as_[16][132];
    int tid = threadIdx.x;
    int m0 = blockIdx.x * 16;
    int b = m0 >> 12;
    const size_t cbase = ((size_t)b * CROWS + SLOT0) * DSLOT;

#pragma unroll
    for (int i = 0; i < 4; i++) {
        int f = tid + i * 256;
        int row = f >> 6, c4 = f & 63;
        float4 v = *(const float4*)(query + (size_t)(m0 + row) * DC + c4 * 4);
        *(float4*)&qs[row][c4 * 4] = v;
    }
    int r = tid >> 4, tx = tid & 15;
    float sc[8];
#pragma unroll
    for (int j = 0; j < 8; j++) sc[j] = 0.f;

    for (int d0 = 0; d0 < DC; d0 += 64) {
        __syncthreads();
        for (int idx = tid; idx < 128 * 64; idx += 256) {
            int slot = idx >> 6, dd = idx & 63;
            cs[slot][dd] = cache[cbase + (size_t)slot * DSLOT + d0 + dd];
        }
        __syncthreads();
        for (int dd = 0; dd < 64; dd++) {
            float qv = qs[r][d0 + dd];
#pragma unroll
            for (int j = 0; j < 8; j++) sc[j] += qv * cs[tx + 16 * j][dd];
        }
    }
    float mx = -1e30f;
#pragma unroll
    for (int j = 0; j < 8; j++) {
        sc[j] *= 0.0625f;
        sc[j] = fminf(fmaxf(sc[j], -20.f), 20.f);
        mx = fmaxf(mx, sc[j]);
    }
#pragma unroll
    for (int m = 1; m < 16; m <<= 1) mx = fmaxf(mx, __shfl_xor(mx, m));
    float sum = 0.f;
#pragma unroll
    for (int j = 0; j < 8; j++) { float e = expf(sc[j] - mx); sc[j] = e; sum += e; }
#pragma unroll
    for (int m = 1; m < 16; m <<= 1) sum += __shfl_xor(sum, m);
    float inv = 1.f / sum;
#pragma unroll
    for (int j = 0; j < 8; j++) as_[r][tx + 16 * j] = sc[j] * inv;
    __syncthreads();

#pragma unroll
    for (int i = 0; i < 2; i++) {
        int f = tid + i * 256;
        int row = f >> 5, c4 = f & 31;
        float4 v = *(const float4*)&as_[row][c4 * 4];
        *(float4*)(attn_out + (size_t)(m0 + row) * NSLOT + c4 * 4) = v;
    }

    float* ls = &cs[0][0];
    float ctx[18];
#pragma unroll
    for (int i = 0; i < 18; i++) ctx[i] = 0.f;
    for (int k0 = 0; k0 < NSLOT; k0 += 16) {
        __syncthreads();
        for (int idx = tid; idx < 16 * DSLOT; idx += 256) {
            int kk = idx / DSLOT, c = idx % DSLOT;
            ls[kk * DSLOT + c] = cache[cbase + (size_t)(k0 + kk) * DSLOT + c];
        }
        __syncthreads();
#pragma unroll
        for (int kk = 0; kk < 16; kk++) {
            float a = as_[r][k0 + kk];
#pragma unroll
            for (int i = 0; i < 18; i++) {
                int c = tx + 16 * i;
                if (c < DSLOT) ctx[i] += a * ls[kk * DSLOT + c];
            }
        }
    }
    ushort* crow = ctxb + (size_t)(m0 + r) * KPAD;
#pragma unroll
    for (int i = 0; i < 18; i++) { int c = tx + 16 * i; if (c < DSLOT) crow[c] = f2bf(ctx[i]); }
    if (tx < KPAD - DSLOT) crow[DSLOT + tx] = 0;
}

extern "C" void kernel_launch(void* const* d_in, const int* in_sizes, int n_in,
                              void* d_out, int out_size, void* d_ws, size_t ws_size,
                              hipStream_t stream)
{
    (void)in_sizes; (void)n_in; (void)out_size; (void)ws_size;
    const float* x    = (const float*)d_in[0];
    const float* cache= (const float*)d_in[1];
    const float* lnw  = (const float*)d_in[2];
    const float* lnb  = (const float*)d_in[3];
    const float* g1w  = (const float*)d_in[4];
    const float* g1b  = (const float*)d_in[5];
    const float* g2w  = (const float*)d_in[6];
    const float* g2b  = (const float*)d_in[7];
    const float* rqw  = (const float*)d_in[8];
    const float* rqb  = (const float*)d_in[9];
    const float* fcw  = (const float*)d_in[10];
    const float* fcb  = (const float*)d_in[11];

    float* out   = (float*)d_out;
    float* oxe   = out;
    float* octx  = out + (size_t)MTOT * DM;
    float* oattn = out + (size_t)2 * MTOT * DM;

    float*  ws    = (float*)d_ws;
    float*  mu    = ws;                              // 16384
    float*  rsig  = mu + MTOT;                       // 16384
    float*  logits= rsig + MTOT;                     // 16384
    int*    cnt   = (int*)(logits + MTOT);           // 16
    int*    list  = cnt + 16;                        // 4096
    float*  query = (float*)(list + MAXR);           // 16384*256
    ushort* ctxb  = (ushort*)(query + (size_t)MTOT * DC);   // 16384*288
    ushort* Bh    = ctxb + (size_t)MTOT * KPAD;      // 1024*2048
    ushort* Bl    = Bh + (size_t)DMH * DM;           // 1024*2048
    ushort* rqwt  = Bl + (size_t)DMH * DM;           // 256*2048
    ushort* fcwt  = rqwt + (size_t)DC * DM;          // 2048*288
    ushort* Ah    = fcwt + (size_t)DM * KPAD;        // 16384*2048
    ushort* Al    = Ah + (size_t)MTOT * DM;          // 16384*2048 (xh after gate)

    k_prep_w<<<(DMH * DM) / 256, 256, 0, stream>>>(g1w, rqw, fcw, Bh, Bl, rqwt, fcwt);
    k_ln_stats<<<MTOT, 256, 0, stream>>>(x, mu, rsig, logits, cnt);
    k_prep_a<<<(MTOT * DM / 8) / 256, 256, 0, stream>>>(x, mu, rsig, lnw, lnb, Ah, Al);
    // gate: 3-segment split bf16 MFMA
    k_mfma<0><<<dim3(DMH / 128, MTOT / 128), 256, 0, stream>>>(Ah, Al, Bh, Bl, DM, DMH,
        g1b, g2w, logits, nullptr, nullptr, nullptr, nullptr, nullptr);
    k_compact<<<MTOT / 256, 256, 0, stream>>>(logits, g2b, cnt, list);
    k_prep_xh<<<(MTOT * DM / 8) / 256, 256, 0, stream>>>(x, Al);
    k_refine<<<512, 256, 0, stream>>>(x, mu, rsig, lnw, lnb, g1w, g1b, g2w, list, cnt, logits);
    // query = x @ rq_w + rq_b
    k_mfma<1><<<dim3(DC / 128, MTOT / 128), 256, 0, stream>>>(Al, nullptr, rqwt, nullptr, DM, DC,
        nullptr, nullptr, nullptr, rqb, query, nullptr, nullptr, nullptr);
    k_attn<<<MTOT / 16, 256, 0, stream>>>(query, cache, oattn, ctxb);
    // context + x_enhanced
    k_mfma<2><<<dim3(DM / 128, MTOT / 128), 256, 0, stream>>>(ctxb, nullptr, fcwt, nullptr, KPAD, DM,
        nullptr, nullptr, logits, fcb, octx, x, oxe, g2b);
}

// Round 3
// 1052.298 us; speedup vs baseline: 1.7476x; 1.1449x over previous
//
#include <hip/hip_runtime.h>
#include <math.h>

#define DM     2048
#define DMH    1024
#define DC     256
#define NSLOT  128
#define DSLOT  273
#define KPAD   288
#define MTOT   16384
#define CROWS  1536
#define SLOT0  384
#define MAXR   8192
#define TAU    0.025f

typedef __attribute__((ext_vector_type(8))) short  short8;
typedef __attribute__((ext_vector_type(8))) __bf16 bf16x8;
typedef __attribute__((ext_vector_type(4))) float  f32x4;

__device__ inline ushort f2bf(float f) {
    unsigned u = __builtin_bit_cast(unsigned, f);
    unsigned r = (u + 0x7FFFu + ((u >> 16) & 1u)) >> 16;   // RNE
    return (ushort)r;
}
__device__ inline float bf2f(ushort h) {
    unsigned u = ((unsigned)h) << 16;
    return __builtin_bit_cast(float, u);
}

// ---- fused: LN stats + Ah = bf16(LN(x)) + xh = bf16(x); init logits/cnt ----
__global__ __launch_bounds__(256) void k_lnprep(const float* __restrict__ x,
    const float* __restrict__ lnw, const float* __restrict__ lnb,
    float* __restrict__ mu, float* __restrict__ rsig, float* __restrict__ logits,
    int* __restrict__ cnt, ushort* __restrict__ Ah, ushort* __restrict__ xh)
{
    int row = blockIdx.x;
    int t = threadIdx.x;
    int c = t * 8;
    const float* xp = x + (size_t)row * DM + c;
    float4 a = *(const float4*)xp, b = *(const float4*)(xp + 4);
    float xr[8] = {a.x, a.y, a.z, a.w, b.x, b.y, b.z, b.w};

    float s = xr[0]+xr[1]+xr[2]+xr[3]+xr[4]+xr[5]+xr[6]+xr[7];
#pragma unroll
    for (int m = 1; m < 64; m <<= 1) s += __shfl_xor(s, m);
    __shared__ float red[4];
    if ((t & 63) == 0) red[t >> 6] = s;
    __syncthreads();
    float mean = (red[0] + red[1] + red[2] + red[3]) * (1.0f / DM);
    float q = 0.f;
#pragma unroll
    for (int e = 0; e < 8; e++) { float d = xr[e] - mean; q += d * d; }
#pragma unroll
    for (int m = 1; m < 64; m <<= 1) q += __shfl_xor(q, m);
    __syncthreads();
    if ((t & 63) == 0) red[t >> 6] = q;
    __syncthreads();
    float var = (red[0] + red[1] + red[2] + red[3]) * (1.0f / DM);
    float rs = rsqrtf(var + 1e-5f);

    float4 w0 = *(const float4*)(lnw + c), w1 = *(const float4*)(lnw + c + 4);
    float4 b0 = *(const float4*)(lnb + c), b1 = *(const float4*)(lnb + c + 4);
    float wv[8] = {w0.x,w0.y,w0.z,w0.w,w1.x,w1.y,w1.z,w1.w};
    float bv[8] = {b0.x,b0.y,b0.z,b0.w,b1.x,b1.y,b1.z,b1.w};
    ushort h[8]; uint4 oh, ox;
#pragma unroll
    for (int e = 0; e < 8; e++) h[e] = f2bf((xr[e] - mean) * rs * wv[e] + bv[e]);
    oh.x = h[0] | ((unsigned)h[1] << 16); oh.y = h[2] | ((unsigned)h[3] << 16);
    oh.z = h[4] | ((unsigned)h[5] << 16); oh.w = h[6] | ((unsigned)h[7] << 16);
#pragma unroll
    for (int e = 0; e < 8; e++) h[e] = f2bf(xr[e]);
    ox.x = h[0] | ((unsigned)h[1] << 16); ox.y = h[2] | ((unsigned)h[3] << 16);
    ox.z = h[4] | ((unsigned)h[5] << 16); ox.w = h[6] | ((unsigned)h[7] << 16);
    size_t base = (size_t)row * DM + c;
    *(uint4*)(Ah + base) = oh;
    *(uint4*)(xh + base) = ox;
    if (t == 0) { mu[row] = mean; rsig[row] = rs; logits[row] = 0.f; }
    if (row == 0 && t == 0) *cnt = 0;
}

// ---- weights: convert + transpose to B^T [N][K] bf16 ----
__global__ __launch_bounds__(256) void k_prep_w(const float* __restrict__ g1w,
    const float* __restrict__ rqw, const float* __restrict__ fcw,
    ushort* __restrict__ Bh, ushort* __restrict__ rqwt, ushort* __restrict__ fcwt)
{
    int idx = blockIdx.x * 256 + threadIdx.x;     // 2,097,152 total
    {   // g1w [2048][1024] -> [1024][2048]
        int nn = idx >> 11, k = idx & 2047;
        Bh[idx] = f2bf(g1w[(size_t)k * DMH + nn]);
    }
    if (idx < DC * DM) {        // rqw [2048][256] -> [256][2048]
        int nn = idx >> 11, k = idx & 2047;
        rqwt[idx] = f2bf(rqw[(size_t)k * DC + nn]);
    }
    if (idx < DM * KPAD) {      // fcw [273][2048] -> [2048][288] zero-padded
        int nn = idx / KPAD, kk = idx - nn * KPAD;
        fcwt[idx] = (kk < DSLOT) ? f2bf(fcw[(size_t)kk * DM + nn]) : (ushort)0;
    }
}

// ---- bf16 MFMA GEMM, 128x128 tile, BK=32 ----
// MODE 0: gate; epilogue silu(.+g1b).g2w -> atomicAdd logits
// MODE 1: query: acc + bias -> outc fp32 (LDS-vectorized epilogue)
// MODE 2: fc: acc + bias -> outc; outxe = xin + gate*val
template<int MODE>
__global__ __launch_bounds__(256) void k_mfma(
    const ushort* __restrict__ A0, const ushort* __restrict__ B0,
    int K, int N,
    const float* __restrict__ g1b, const float* __restrict__ g2w,
    float* __restrict__ logits,
    const float* __restrict__ bias, float* __restrict__ outc,
    const float* __restrict__ xin, float* __restrict__ outxe,
    const float* __restrict__ g2b)
{
    __shared__ __align__(16) ushort smem[8448];   // 16896 B: staging (16384) / epilogue (16896)
    ushort* Asl = smem;
    ushort* Bsl = smem + 4096;
    int tid = threadIdx.x;
    int wid = tid >> 6, l = tid & 63;
    int m0 = blockIdx.y * 128, n0 = blockIdx.x * 128;
    int m_off = (wid >> 1) * 64, n_off = (wid & 1) * 64;
    int lr = l & 15, lk = l >> 4;
    int arow = l >> 2, ak8 = (l & 3) * 8;

    f32x4 acc[4][4];
#pragma unroll
    for (int i = 0; i < 4; i++)
#pragma unroll
        for (int j = 0; j < 4; j++) acc[i][j] = (f32x4){0.f, 0.f, 0.f, 0.f};

    for (int k0 = 0; k0 < K; k0 += 32) {
#pragma unroll
        for (int q = 0; q < 2; q++) {
            int chunk = q * 4 + wid;
            int row = chunk * 16 + arow;
            const ushort* ga = A0 + (size_t)(m0 + row) * K + k0 + ak8;
            const ushort* gb = B0 + (size_t)(n0 + row) * K + k0 + ak8;
            __builtin_amdgcn_global_load_lds(
                (const __attribute__((address_space(1))) void*)ga,
                (__attribute__((address_space(3))) void*)(Asl + chunk * 512), 16, 0, 0);
            __builtin_amdgcn_global_load_lds(
                (const __attribute__((address_space(1))) void*)gb,
                (__attribute__((address_space(3))) void*)(Bsl + chunk * 512), 16, 0, 0);
        }
        __syncthreads();
        bf16x8 af[4], bfr[4];
#pragma unroll
        for (int i = 0; i < 4; i++)
            af[i] = __builtin_bit_cast(bf16x8, *(const short8*)&Asl[(m_off + i * 16 + lr) * 32 + lk * 8]);
#pragma unroll
        for (int j = 0; j < 4; j++)
            bfr[j] = __builtin_bit_cast(bf16x8, *(const short8*)&Bsl[(n_off + j * 16 + lr) * 32 + lk * 8]);
#pragma unroll
        for (int i = 0; i < 4; i++)
#pragma unroll
            for (int j = 0; j < 4; j++)
                acc[i][j] = __builtin_amdgcn_mfma_f32_16x16x32_bf16(af[i], bfr[j], acc[i][j], 0, 0, 0);
        __syncthreads();
    }

    if (MODE == 0) {
        float gb_[4], gw_[4];
#pragma unroll
        for (int j = 0; j < 4; j++) {
            int c = n0 + n_off + j * 16 + lr;
            gb_[j] = g1b[c]; gw_[j] = g2w[c];
        }
#pragma unroll
        for (int i = 0; i < 4; i++)
#pragma unroll
            for (int v = 0; v < 4; v++) {
                float p = 0.f;
#pragma unroll
                for (int j = 0; j < 4; j++) {
                    float h = acc[i][j][v] + gb_[j];
                    p += (h / (1.f + expf(-h))) * gw_[j];
                }
#pragma unroll
                for (int m = 1; m < 16; m <<= 1) p += __shfl_xor(p, m);
                if (lr == 0) atomicAdd(&logits[m0 + m_off + i * 16 + lk * 4 + v], p);
            }
    } else {
        // LDS-transposed epilogue: coalesced float4 stores
        float* eps = (float*)smem;
        float g2b0 = (MODE == 2) ? g2b[0] : 0.f;
        int rl = (wid >> 1) * 16;                 // 0 or 16
        int rloc = tid >> 3, c0 = (tid & 7) * 16;
        float4 bb[4];
#pragma unroll
        for (int cc = 0; cc < 4; cc++) bb[cc] = *(const float4*)(bias + n0 + c0 + cc * 4);
#pragma unroll
        for (int i = 0; i < 4; i++) {
            __syncthreads();
#pragma unroll
            for (int j = 0; j < 4; j++)
#pragma unroll
                for (int v = 0; v < 4; v++)
                    eps[(rl + lk * 4 + v) * 132 + n_off + j * 16 + lr] = acc[i][j][v];
            __syncthreads();
            int m = m0 + (rloc >> 4) * 64 + i * 16 + (rloc & 15);
            float gt = 0.f;
            if (MODE == 2) gt = (logits[m] + g2b0) > 0.f ? 1.f : 0.f;
            float* orow = outc + (size_t)m * N + n0 + c0;
            const float* xrow = (MODE == 2) ? (xin + (size_t)m * DM + n0 + c0) : nullptr;
            float* erow = (MODE == 2) ? (outxe + (size_t)m * DM + n0 + c0) : nullptr;
#pragma unroll
            for (int cc = 0; cc < 4; cc++) {
                float4 vv = *(float4*)&eps[rloc * 132 + c0 + cc * 4];
                vv.x += bb[cc].x; vv.y += bb[cc].y; vv.z += bb[cc].z; vv.w += bb[cc].w;
                *(float4*)(orow + cc * 4) = vv;
                if (MODE == 2) {
                    float4 xv = *(const float4*)(xrow + cc * 4);
                    float4 ev = {xv.x + gt*vv.x, xv.y + gt*vv.y, xv.z + gt*vv.z, xv.w + gt*vv.w};
                    *(float4*)(erow + cc * 4) = ev;
                }
            }
        }
    }
}

// ---- flag rows with |logit+g2b| < TAU ----
__global__ __launch_bounds__(256) void k_compact(float* __restrict__ logits,
    const float* __restrict__ g2b, int* __restrict__ cnt, int* __restrict__ list)
{
    int i = blockIdx.x * 256 + threadIdx.x;
    float a = logits[i] + g2b[0];
    if (fabsf(a) < TAU) {
        int p = atomicAdd(cnt, 1);
        if (p < MAXR) { list[p] = i; logits[i] = 0.f; }
    }
}

// ---- exact fp32 logit recompute for flagged rows ----
__global__ __launch_bounds__(256) void k_refine(const float* __restrict__ x,
    const float* __restrict__ mu, const float* __restrict__ rsig,
    const float* __restrict__ lnw, const float* __restrict__ lnb,
    const float* __restrict__ g1w, const float* __restrict__ g1b,
    const float* __restrict__ g2w,
    const int* __restrict__ list, const int* __restrict__ cnt,
    float* __restrict__ logits)
{
    __shared__ float lnx[DM];
    __shared__ float red[256];
    int tid = threadIdx.x;
    int n = *cnt; if (n > MAXR) n = MAXR;
    int ntask = n * 8;
    for (int t = blockIdx.x; t < ntask; t += gridDim.x) {
        int row = list[t >> 3], sl = t & 7;
        float mm = mu[row], rs = rsig[row];
        {
            int c = tid * 8;
            const float* xp = x + (size_t)row * DM + c;
            float4 a = *(const float4*)xp, b = *(const float4*)(xp + 4);
            float4 w0 = *(const float4*)(lnw + c), w1 = *(const float4*)(lnw + c + 4);
            float4 b0 = *(const float4*)(lnb + c), b1 = *(const float4*)(lnb + c + 4);
            lnx[c+0] = (a.x-mm)*rs*w0.x+b0.x; lnx[c+1] = (a.y-mm)*rs*w0.y+b0.y;
            lnx[c+2] = (a.z-mm)*rs*w0.z+b0.z; lnx[c+3] = (a.w-mm)*rs*w0.w+b0.w;
            lnx[c+4] = (b.x-mm)*rs*w1.x+b1.x; lnx[c+5] = (b.y-mm)*rs*w1.y+b1.y;
            lnx[c+6] = (b.z-mm)*rs*w1.z+b1.z; lnx[c+7] = (b.w-mm)*rs*w1.w+b1.w;
        }
        __syncthreads();
        int j0 = tid & 127, half = tid >> 7;
        int col = sl * 128 + j0;
        const float* gp = g1w + (size_t)(half * 1024) * DMH + col;
        const float* lp = lnx + half * 1024;
        float s = 0.f;
#pragma unroll 4
        for (int k = 0; k < 1024; k++) s += lp[k] * gp[(size_t)k * DMH];
        red[tid] = s;
        __syncthreads();
        if (tid < 128) {
            float h = red[tid] + red[tid + 128] + g1b[col];
            float p = (h / (1.f + expf(-h))) * g2w[col];
#pragma unroll
            for (int m = 1; m < 64; m <<= 1) p += __shfl_xor(p, m);
            red[tid] = p;
        }
        __syncthreads();
        if (tid == 0) atomicAdd(&logits[row], red[0] + red[64]);
        __syncthreads();
    }
}

// ---- attention: 16 q-rows per block, 128 slots ----
__global__ __launch_bounds__(256) void k_attn(const float* __restrict__ query,
    const float* __restrict__ cache, float* __restrict__ attn_out, ushort* __restrict__ ctxb)
{
    __shared__ float qs[16][260];
    __shared__ float cs[128][68];
    __shared__ float as_[16][132];
    int tid = threadIdx.x;
    int m0 = blockIdx.x * 16;
    int b = m0 >> 12;
    const size_t cbase = ((size_t)b * CROWS + SLOT0) * DSLOT;

#pragma unroll
    for (int i = 0; i < 4; i++) {
        int f = tid + i * 256;
        int row = f >> 6, c4 = f & 63;
        float4 v = *(const float4*)(query + (size_t)(m0 + row) * DC + c4 * 4);
        *(float4*)&qs[row][c4 * 4] = v;
    }
    int r = tid >> 4, tx = tid & 15;
    float sc[8];
#pragma unroll
    for (int j = 0; j < 8; j++) sc[j] = 0.f;

    for (int d0 = 0; d0 < DC; d0 += 64) {
        __syncthreads();
        for (int idx = tid; idx < 128 * 64; idx += 256) {
            int slot = idx >> 6, dd = idx & 63;
            cs[slot][dd] = cache[cbase + (size_t)slot * DSLOT + d0 + dd];
        }
        __syncthreads();
        for (int dd = 0; dd < 64; dd++) {
            float qv = qs[r][d0 + dd];
#pragma unroll
            for (int j = 0; j < 8; j++) sc[j] += qv * cs[tx + 16 * j][dd];
        }
    }
    float mx = -1e30f;
#pragma unroll
    for (int j = 0; j < 8; j++) {
        sc[j] *= 0.0625f;
        sc[j] = fminf(fmaxf(sc[j], -20.f), 20.f);
        mx = fmaxf(mx, sc[j]);
    }
#pragma unroll
    for (int m = 1; m < 16; m <<= 1) mx = fmaxf(mx, __shfl_xor(mx, m));
    float sum = 0.f;
#pragma unroll
    for (int j = 0; j < 8; j++) { float e = expf(sc[j] - mx); sc[j] = e; sum += e; }
#pragma unroll
    for (int m = 1; m < 16; m <<= 1) sum += __shfl_xor(sum, m);
    float inv = 1.f / sum;
#pragma unroll
    for (int j = 0; j < 8; j++) as_[r][tx + 16 * j] = sc[j] * inv;
    __syncthreads();

#pragma unroll
    for (int i = 0; i < 2; i++) {
        int f = tid + i * 256;
        int row = f >> 5, c4 = f & 31;
        float4 v = *(const float4*)&as_[row][c4 * 4];
        *(float4*)(attn_out + (size_t)(m0 + row) * NSLOT + c4 * 4) = v;
    }

    // PV: context_full[16][273] = attn @ local (16-slot tiles, div-free staging)
    float* ls = &cs[0][0];
    float ctx[18];
#pragma unroll
    for (int i = 0; i < 18; i++) ctx[i] = 0.f;
    for (int k0 = 0; k0 < NSLOT; k0 += 16) {
        __syncthreads();
        const float* src = cache + cbase + (size_t)(k0 + r) * DSLOT;
#pragma unroll
        for (int i = 0; i < 18; i++) {
            int c = tx + 16 * i;
            if (c < DSLOT) ls[r * DSLOT + c] = src[c];
        }
        __syncthreads();
#pragma unroll
        for (int kk = 0; kk < 16; kk++) {
            float a = as_[r][k0 + kk];
#pragma unroll
            for (int i = 0; i < 18; i++) {
                int c = tx + 16 * i;
                if (c < DSLOT) ctx[i] += a * ls[kk * DSLOT + c];
            }
        }
    }
    ushort* crow = ctxb + (size_t)(m0 + r) * KPAD;
#pragma unroll
    for (int i = 0; i < 18; i++) { int c = tx + 16 * i; if (c < DSLOT) crow[c] = f2bf(ctx[i]); }
    if (tx < KPAD - DSLOT) crow[DSLOT + tx] = 0;
}

extern "C" void kernel_launch(void* const* d_in, const int* in_sizes, int n_in,
                              void* d_out, int out_size, void* d_ws, size_t ws_size,
                              hipStream_t stream)
{
    (void)in_sizes; (void)n_in; (void)out_size; (void)ws_size;
    const float* x    = (const float*)d_in[0];
    const float* cache= (const float*)d_in[1];
    const float* lnw  = (const float*)d_in[2];
    const float* lnb  = (const float*)d_in[3];
    const float* g1w  = (const float*)d_in[4];
    const float* g1b  = (const float*)d_in[5];
    const float* g2w  = (const float*)d_in[6];
    const float* g2b  = (const float*)d_in[7];
    const float* rqw  = (const float*)d_in[8];
    const float* rqb  = (const float*)d_in[9];
    const float* fcw  = (const float*)d_in[10];
    const float* fcb  = (const float*)d_in[11];

    float* out   = (float*)d_out;
    float* oxe   = out;
    float* octx  = out + (size_t)MTOT * DM;
    float* oattn = out + (size_t)2 * MTOT * DM;

    float*  ws    = (float*)d_ws;
    float*  mu    = ws;                              // 16384
    float*  rsig  = mu + MTOT;                       // 16384
    float*  logits= rsig + MTOT;                     // 16384
    int*    cnt   = (int*)(logits + MTOT);           // 16
    int*    list  = cnt + 16;                        // 8192
    float*  query = (float*)(list + MAXR);           // 16384*256 f32
    ushort* ctxb  = (ushort*)(query + (size_t)MTOT * DC);   // 16384*288
    ushort* Bh    = ctxb + (size_t)MTOT * KPAD;      // 1024*2048
    ushort* rqwt  = Bh + (size_t)DMH * DM;           // 256*2048
    ushort* fcwt  = rqwt + (size_t)DC * DM;          // 2048*288
    ushort* Ah    = fcwt + (size_t)DM * KPAD;        // 16384*2048
    ushort* xh    = Ah + (size_t)MTOT * DM;          // 16384*2048

    k_prep_w<<<(DMH * DM) / 256, 256, 0, stream>>>(g1w, rqw, fcw, Bh, rqwt, fcwt);
    k_lnprep<<<MTOT, 256, 0, stream>>>(x, lnw, lnb, mu, rsig, logits, cnt, Ah, xh);
    // gate: single-segment bf16 MFMA (+ fp32 refine for |logit|<TAU rows)
    k_mfma<0><<<dim3(DMH / 128, MTOT / 128), 256, 0, stream>>>(Ah, Bh, DM, DMH,
        g1b, g2w, logits, nullptr, nullptr, nullptr, nullptr, nullptr);
    k_compact<<<MTOT / 256, 256, 0, stream>>>(logits, g2b, cnt, list);
    k_refine<<<1024, 256, 0, stream>>>(x, mu, rsig, lnw, lnb, g1w, g1b, g2w, list, cnt, logits);
    // query = x @ rq_w + rq_b
    k_mfma<1><<<dim3(DC / 128, MTOT / 128), 256, 0, stream>>>(xh, rqwt, DM, DC,
        nullptr, nullptr, nullptr, rqb, query, nullptr, nullptr, nullptr);
    k_attn<<<MTOT / 16, 256, 0, stream>>>(query, cache, oattn, ctxb);
    // context + x_enhanced
    k_mfma<2><<<dim3(DM / 128, MTOT / 128), 256, 0, stream>>>(ctxb, fcwt, KPAD, DM,
        nullptr, nullptr, logits, fcb, octx, x, oxe, g2b);
}